// Round 1
// baseline (189.966 us; speedup 1.0000x reference)
//
#include <hip/hip_runtime.h>

typedef unsigned short u16;
typedef __bf16 b16;
typedef b16 b16x8 __attribute__((ext_vector_type(8)));
typedef float f32x4 __attribute__((ext_vector_type(4)));
typedef u16 u16x4 __attribute__((ext_vector_type(4)));
typedef u16 u16x8 __attribute__((ext_vector_type(8)));
typedef float f4 __attribute__((ext_vector_type(4)));

#define NH 8
#define SEQ 4096
#define DM 512
#define HDIM 64
#define GM 8192      // B*S
#define GK 512       // D
#define GN 1536      // 3*D

__device__ __forceinline__ u16 f2bf(float f) {
  union { float f; unsigned u; } v; v.f = f;
  unsigned r = v.u + 0x7FFFu + ((v.u >> 16) & 1u);
  return (u16)(r >> 16);
}

// ---------------- conversion: inputs f32 -> bf16 (row-major 8192x512) ----------------
__global__ __launch_bounds__(256) void cvt_inputs(const float* __restrict__ x,
                                                  u16* __restrict__ y, int n) {
  int i = (blockIdx.x * 256 + threadIdx.x) * 4;
  if (i < n) {
    f4 v = *(const f4*)(x + i);
    u16x4 o;
    o[0] = f2bf(v[0]); o[1] = f2bf(v[1]); o[2] = f2bf(v[2]); o[3] = f2bf(v[3]);
    *(u16x4*)(y + i) = o;
  }
}

// ---------------- conversion+transpose: W (512x1536 f32) -> Wt (1536x512 bf16) -------
__global__ __launch_bounds__(256) void cvt_w(const float* __restrict__ w,
                                             u16* __restrict__ wt) {
  __shared__ float tile[32][33];
  int n0 = blockIdx.x * 32;   // over 1536 (48 blocks)
  int k0 = blockIdx.y * 32;   // over 512  (16 blocks)
  int t = threadIdx.x;
  int tn = t & 31, tk = t >> 5;   // 8 rows per pass
#pragma unroll
  for (int p = 0; p < 4; ++p) {
    int k = tk + p * 8;
    tile[k][tn] = w[(k0 + k) * GN + n0 + tn];
  }
  __syncthreads();
  int n_l = t >> 3, kg = (t & 7) * 4;
  u16x4 o;
#pragma unroll
  for (int i = 0; i < 4; ++i) o[i] = f2bf(tile[kg + i][n_l]);
  *(u16x4*)(wt + (n0 + n_l) * GK + k0 + kg) = o;
}

// ---------------- QKV GEMM: A(8192x512) x Wt(1536x512)^T -> Q,K,V (B,H,S,64) bf16 ----
__global__ __launch_bounds__(256) void qkv_gemm(const u16* __restrict__ A,
                                                const u16* __restrict__ Wt,
                                                u16* __restrict__ Q,
                                                u16* __restrict__ K,
                                                u16* __restrict__ V) {
  __shared__ __align__(16) u16 As[128 * 32];
  __shared__ __align__(16) u16 Bs[128 * 32];
  int bm = blockIdx.x * 128;   // 64 tiles
  int bn = blockIdx.y * 128;   // 12 tiles
  int t = threadIdx.x;
  int lane = t & 63, w = t >> 6;
  int wr = w >> 1, wc = w & 1;
  int l15 = lane & 15, g = lane >> 4;

  f32x4 acc[4][4];
#pragma unroll
  for (int i = 0; i < 4; ++i)
#pragma unroll
    for (int j = 0; j < 4; ++j) {
      acc[i][j][0] = 0.f; acc[i][j][1] = 0.f; acc[i][j][2] = 0.f; acc[i][j][3] = 0.f;
    }

  for (int k0 = 0; k0 < GK; k0 += 32) {
    // stage A and B tiles (reg-staged, 2x16B each per thread per matrix)
#pragma unroll
    for (int j = 0; j < 2; ++j) {
      int cid = t * 2 + j;
      int row = cid >> 2, co = (cid & 3) * 8;
      u16x8 va = *(const u16x8*)(A + (bm + row) * GK + k0 + co);
      u16x8 vb = *(const u16x8*)(Wt + (bn + row) * GK + k0 + co);
      *(u16x8*)(As + row * 32 + co) = va;
      *(u16x8*)(Bs + row * 32 + co) = vb;
    }
    __syncthreads();
    b16x8 af[4], bf[4];
#pragma unroll
    for (int mi = 0; mi < 4; ++mi)
      af[mi] = *(const b16x8*)(As + (wr * 64 + mi * 16 + l15) * 32 + g * 8);
#pragma unroll
    for (int ni = 0; ni < 4; ++ni)
      bf[ni] = *(const b16x8*)(Bs + (wc * 64 + ni * 16 + l15) * 32 + g * 8);
#pragma unroll
    for (int mi = 0; mi < 4; ++mi)
#pragma unroll
      for (int ni = 0; ni < 4; ++ni)
        acc[mi][ni] = __builtin_amdgcn_mfma_f32_16x16x32_bf16(af[mi], bf[ni], acc[mi][ni], 0, 0, 0);
    __syncthreads();
  }

  // epilogue: scatter to Q/K/V as (B,H,S,64) bf16
#pragma unroll
  for (int mi = 0; mi < 4; ++mi)
#pragma unroll
    for (int ni = 0; ni < 4; ++ni) {
      int e = bn + wc * 64 + ni * 16 + l15;
      int which = e >> 9, col = e & 511;
      int h = col >> 6, dd = col & 63;
      u16* dst = which == 0 ? Q : (which == 1 ? K : V);
#pragma unroll
      for (int r = 0; r < 4; ++r) {
        int m = bm + wr * 64 + mi * 16 + g * 4 + r;
        int b = m >> 12, s = m & 4095;
        dst[(((b * NH + h) * SEQ) + s) * HDIM + dd] = f2bf(acc[mi][ni][r]);
      }
    }
}

// ---------------- flash attention, causal, 64 q-rows/block, KV tile = 64 -------------
__global__ __launch_bounds__(256) void attn(const u16* __restrict__ Q,
                                            const u16* __restrict__ Kv,
                                            const u16* __restrict__ Vv,
                                            float* __restrict__ out) {
  int id = blockIdx.x;
  int bh = id & 15;            // b*8+h
  int qt = 63 - (id >> 4);     // heavy diagonal tiles first
  int b = bh >> 3, h = bh & 7;
  const u16* Qb = Q + (size_t)bh * SEQ * HDIM;
  const u16* Kb = Kv + (size_t)bh * SEQ * HDIM;
  const u16* Vb = Vv + (size_t)bh * SEQ * HDIM;
  int t = threadIdx.x, lane = t & 63, w = t >> 6;
  int l15 = lane & 15, g = lane >> 4;
  int qb = qt * 64;
  int qw = qb + w * 16;

  __shared__ __align__(16) u16 Ks[64 * 72];
  __shared__ __align__(16) u16 Vt[64 * 72];   // Vt[dd][j]
  __shared__ __align__(16) u16 Ps[4 * 16 * 72];

  // Q fragments (A-operand): row = lane&15, k = g*8..+7 (+32 per slice)
  b16x8 qf[2];
#pragma unroll
  for (int ks = 0; ks < 2; ++ks)
    qf[ks] = *(const b16x8*)(Qb + (qw + l15) * HDIM + ks * 32 + g * 8);

  f32x4 oacc[4];
#pragma unroll
  for (int i = 0; i < 4; ++i) { oacc[i][0] = 0.f; oacc[i][1] = 0.f; oacc[i][2] = 0.f; oacc[i][3] = 0.f; }
  float m[4], l[4];
#pragma unroll
  for (int r = 0; r < 4; ++r) { m[r] = -1e30f; l[r] = 0.f; }

  for (int j0 = 0; j0 <= qb; j0 += 64) {
    // ---- stage K (row-major, pad 72) and V^T ----
    {
      int row = t >> 2, c0 = (t & 3) * 16;
      u16x8 k0v = *(const u16x8*)(Kb + (j0 + row) * HDIM + c0);
      u16x8 k1v = *(const u16x8*)(Kb + (j0 + row) * HDIM + c0 + 8);
      *(u16x8*)(Ks + row * 72 + c0) = k0v;
      *(u16x8*)(Ks + row * 72 + c0 + 8) = k1v;
      u16x8 v0v = *(const u16x8*)(Vb + (j0 + row) * HDIM + c0);
      u16x8 v1v = *(const u16x8*)(Vb + (j0 + row) * HDIM + c0 + 8);
#pragma unroll
      for (int i = 0; i < 8; ++i) Vt[(c0 + i) * 72 + row] = v0v[i];
#pragma unroll
      for (int i = 0; i < 8; ++i) Vt[(c0 + 8 + i) * 72 + row] = v1v[i];
    }
    __syncthreads();

    // ---- S = Q K^T : 4 col-tiles x 2 k-slices ----
    f32x4 sa[4];
#pragma unroll
    for (int c = 0; c < 4; ++c) { sa[c][0] = 0.f; sa[c][1] = 0.f; sa[c][2] = 0.f; sa[c][3] = 0.f; }
#pragma unroll
    for (int c = 0; c < 4; ++c)
#pragma unroll
      for (int ks = 0; ks < 2; ++ks) {
        b16x8 kf = *(const b16x8*)(Ks + (c * 16 + l15) * 72 + ks * 32 + g * 8);
        sa[c] = __builtin_amdgcn_mfma_f32_16x16x32_bf16(qf[ks], kf, sa[c], 0, 0, 0);
      }

    // ---- scale + causal mask (only the diagonal tile has masked elems) ----
    bool diag = (j0 == qb);
#pragma unroll
    for (int c = 0; c < 4; ++c)
#pragma unroll
      for (int r = 0; r < 4; ++r) {
        float sv = sa[c][r] * 0.125f;
        if (diag) {
          int jj = j0 + c * 16 + l15;
          int qq = qw + g * 4 + r;
          if (jj > qq) sv = -1e30f;
        }
        sa[c][r] = sv;
      }

    // ---- online softmax: row = (g*4+r), cols across lane&15 within 16-lane group ----
    float rmax[4];
#pragma unroll
    for (int r = 0; r < 4; ++r)
      rmax[r] = fmaxf(fmaxf(sa[0][r], sa[1][r]), fmaxf(sa[2][r], sa[3][r]));
#pragma unroll
    for (int d = 1; d < 16; d <<= 1)
#pragma unroll
      for (int r = 0; r < 4; ++r)
        rmax[r] = fmaxf(rmax[r], __shfl_xor(rmax[r], d));
    float alpha[4];
#pragma unroll
    for (int r = 0; r < 4; ++r) {
      float mn = fmaxf(m[r], rmax[r]);
      alpha[r] = __expf(m[r] - mn);
      m[r] = mn;
    }
    // P = exp(s - m), store bf16 to per-wave LDS region
#pragma unroll
    for (int c = 0; c < 4; ++c)
#pragma unroll
      for (int r = 0; r < 4; ++r) {
        float p = __expf(sa[c][r] - m[r]);
        sa[c][r] = p;
        Ps[(w * 16 + g * 4 + r) * 72 + c * 16 + l15] = f2bf(p);
      }
    float rsum[4];
#pragma unroll
    for (int r = 0; r < 4; ++r)
      rsum[r] = (sa[0][r] + sa[1][r]) + (sa[2][r] + sa[3][r]);
#pragma unroll
    for (int d = 1; d < 16; d <<= 1)
#pragma unroll
      for (int r = 0; r < 4; ++r)
        rsum[r] += __shfl_xor(rsum[r], d);
#pragma unroll
    for (int r = 0; r < 4; ++r)
      l[r] = l[r] * alpha[r] + rsum[r];
#pragma unroll
    for (int tdd = 0; tdd < 4; ++tdd)
#pragma unroll
      for (int r = 0; r < 4; ++r)
        oacc[tdd][r] *= alpha[r];

    // ---- PV: O += P(16x64) * V(64x64), A-frags from Ps, B-frags from Vt ----
#pragma unroll
    for (int js = 0; js < 2; ++js) {
      b16x8 pf = *(const b16x8*)(Ps + (w * 16 + l15) * 72 + js * 32 + g * 8);
#pragma unroll
      for (int tdd = 0; tdd < 4; ++tdd) {
        b16x8 vf = *(const b16x8*)(Vt + (tdd * 16 + l15) * 72 + js * 32 + g * 8);
        oacc[tdd] = __builtin_amdgcn_mfma_f32_16x16x32_bf16(pf, vf, oacc[tdd], 0, 0, 0);
      }
    }
    __syncthreads();
  }

  // ---- epilogue: out (B,S,H*64) f32 ----
  float inv[4];
#pragma unroll
  for (int r = 0; r < 4; ++r) inv[r] = 1.0f / l[r];
#pragma unroll
  for (int tdd = 0; tdd < 4; ++tdd)
#pragma unroll
    for (int r = 0; r < 4; ++r) {
      int q = qw + g * 4 + r;
      int dd = tdd * 16 + l15;
      out[((size_t)b * SEQ + q) * DM + h * HDIM + dd] = oacc[tdd][r] * inv[r];
    }
}

extern "C" void kernel_launch(void* const* d_in, const int* in_sizes, int n_in,
                              void* d_out, int out_size, void* d_ws, size_t ws_size,
                              hipStream_t stream) {
  const float* x = (const float*)d_in[0];       // (2,4096,512) f32
  const float* wq = (const float*)d_in[1];      // (512,1536) f32
  float* out = (float*)d_out;                   // (2,4096,512) f32
  char* ws = (char*)d_ws;

  u16* A  = (u16*)ws;                                   // 8192x512 bf16   (8.39 MB)
  u16* Wt = (u16*)(ws + 8388608);                       // 1536x512 bf16   (1.57 MB)
  u16* Qw = (u16*)(ws + 8388608 + 1572864);             // (B,H,S,64) bf16 (8.39 MB)
  u16* Kw = Qw + 4194304;
  u16* Vw = Kw + 4194304;

  cvt_inputs<<<4096, 256, 0, stream>>>(x, A, GM * GK);
  dim3 gw(48, 16);
  cvt_w<<<gw, 256, 0, stream>>>(wq, Wt);
  dim3 gg(64, 12);
  qkv_gemm<<<gg, 256, 0, stream>>>(A, Wt, Qw, Kw, Vw);
  attn<<<1024, 256, 0, stream>>>(Qw, Kw, Vw, out);
}